// Round 5
// baseline (145.012 us; speedup 1.0000x reference)
//
#include <hip/hip_runtime.h>

#define NJ 22

// 6D continuous rotation -> 3x3 row-major rotation matrix (columns b1,b2,b3)
__device__ __forceinline__ void rot6d_to_mat(float a1x, float a1y, float a1z,
                                             float a2x, float a2y, float a2z,
                                             float* R) {
    float n1 = sqrtf(a1x * a1x + a1y * a1y + a1z * a1z);
    float inv1 = 1.0f / fmaxf(n1, 1e-12f);
    float b1x = a1x * inv1, b1y = a1y * inv1, b1z = a1z * inv1;
    float d = b1x * a2x + b1y * a2y + b1z * a2z;
    float b2x = a2x - b1x * d, b2y = a2y - b1y * d, b2z = a2z - b1z * d;
    float n2 = sqrtf(b2x * b2x + b2y * b2y + b2z * b2z);
    float inv2 = 1.0f / fmaxf(n2, 1e-12f);
    b2x *= inv2; b2y *= inv2; b2z *= inv2;
    float b3x = b1y * b2z - b1z * b2y;
    float b3y = b1z * b2x - b1x * b2z;
    float b3z = b1x * b2y - b1y * b2x;
    // columns are b1, b2, b3
    R[0] = b1x; R[1] = b2x; R[2] = b3x;
    R[3] = b1y; R[4] = b2y; R[5] = b3y;
    R[6] = b1z; R[7] = b2z; R[8] = b3z;
}

__device__ __forceinline__ void matmul3(const float* __restrict__ A,
                                        const float* __restrict__ B,
                                        float* __restrict__ C) {
#pragma unroll
    for (int r = 0; r < 3; ++r) {
#pragma unroll
        for (int c = 0; c < 3; ++c) {
            C[r * 3 + c] = A[r * 3 + 0] * B[0 * 3 + c]
                         + A[r * 3 + 1] * B[1 * 3 + c]
                         + A[r * 3 + 2] * B[2 * 3 + c];
        }
    }
}

// One FK walk step: joint j. Semantics (matches reference):
//   if reset: R=I, P=0                        (restart at root)
//   P  = P + R @ offsets[j]                   (R == g_rot[parent(j)])
//   if emit: sum += |pred[j-2] - P|           (dist for joint j)
//   if upR:  R = R @ M_j                      (R becomes g_rot[j]; loads gt_rot[j])
struct Step { int j; int reset; int emit; int upR; };

template<int ROLE> struct RoleDef;
// T0: dists {2,3,4,7,10}; records {4,7}
template<> struct RoleDef<0> {
    static constexpr int NS = 6;
    static constexpr Step S[6] = {{2,1,1,0},{3,1,1,0},{1,1,0,0},{4,0,1,1},{7,0,1,1},{10,0,1,0}};
};
// T1: dists {5,8,11}; records {2,5,8}
template<> struct RoleDef<1> {
    static constexpr int NS = 4;
    static constexpr Step S[4] = {{2,1,0,1},{5,0,1,1},{8,0,1,1},{11,0,1,0}};
};
// T2: dists {6,9,12,15}; records {3,6,9,12}
template<> struct RoleDef<2> {
    static constexpr int NS = 5;
    static constexpr Step S[5] = {{3,1,0,1},{6,0,1,1},{9,0,1,1},{12,0,1,1},{15,0,1,0}};
};
// T3: dists {13,16,18,20}; records {3,6,9,13,16,18}
template<> struct RoleDef<3> {
    static constexpr int NS = 7;
    static constexpr Step S[7] = {{3,1,0,1},{6,0,0,1},{9,0,0,1},{13,0,1,1},{16,0,1,1},{18,0,1,1},{20,0,1,0}};
};
// T4: dists {14,17,19,21}; records {3,6,9,14,17,19}
template<> struct RoleDef<4> {
    static constexpr int NS = 7;
    static constexpr Step S[7] = {{3,1,0,1},{6,0,0,1},{9,0,0,1},{14,0,1,1},{17,0,1,1},{19,0,1,1},{21,0,1,0}};
};

template<int ROLE>
__device__ __forceinline__ float walk(const float* __restrict__ gr,
                                      const float* __restrict__ pp,
                                      const float* __restrict__ off) {
    float R[9] = {1.f,0.f,0.f, 0.f,1.f,0.f, 0.f,0.f,1.f};
    float P[3] = {0.f,0.f,0.f};
    float sum = 0.f;
#pragma unroll
    for (int s = 0; s < RoleDef<ROLE>::NS; ++s) {
        const int j = RoleDef<ROLE>::S[s].j;               // compile-time after unroll
        if (RoleDef<ROLE>::S[s].reset) {
            R[0]=1.f;R[1]=0.f;R[2]=0.f;R[3]=0.f;R[4]=1.f;R[5]=0.f;R[6]=0.f;R[7]=0.f;R[8]=1.f;
            P[0]=0.f;P[1]=0.f;P[2]=0.f;
        }
        float ox = off[j*3+0], oy = off[j*3+1], oz = off[j*3+2];
        float nx = P[0] + R[0]*ox + R[1]*oy + R[2]*oz;
        float ny = P[1] + R[3]*ox + R[4]*oy + R[5]*oz;
        float nz = P[2] + R[6]*ox + R[7]*oy + R[8]*oz;
        P[0]=nx; P[1]=ny; P[2]=nz;
        if (RoleDef<ROLE>::S[s].emit) {
            const float* q = pp + (j-2)*3;
            float dx = q[0]-nx, dy = q[1]-ny, dz = q[2]-nz;
            sum += sqrtf(dx*dx + dy*dy + dz*dz);
        }
        if (RoleDef<ROLE>::S[s].upR) {
            const float2* g2 = (const float2*)(gr + j*6);  // 24B record stride, 8B aligned
            float2 v0 = g2[0], v1 = g2[1], v2 = g2[2];
            float M[9];
            rot6d_to_mat(v0.x, v0.y, v1.x, v1.y, v2.x, v2.y, M);
            float T[9];
            matmul3(R, M, T);
#pragma unroll
            for (int k = 0; k < 9; ++k) R[k] = T[k];
        }
    }
    return sum;
}

// Block = 320 threads = 5 waves. Wave w handles role w for the block's 64 poses.
// pose = blockIdx.x*64 + lane  -> consecutive lanes read consecutive pose records;
// the 5 role-waves of one block share the same 64-pose gt_rot region (L1 reuse of
// the spine records 3,6,9 that roles 2,3,4 each reload).
__global__ __launch_bounds__(320) void mpjpe_fk_kernel(
    const float* __restrict__ pred_pos,   // [NP, 20, 3]
    const float* __restrict__ gt_rot,     // [NP, 22, 6]
    const float* __restrict__ offsets,    // [22, 3]
    float* __restrict__ out,              // [1]
    int nposes, float scale)              // scale = 1000 / (NP*20)
{
    const int lane = threadIdx.x & 63;
    const int wid  = threadIdx.x >> 6;    // role 0..4
    const int pose = blockIdx.x * 64 + lane;

    float sum = 0.f;
    if (pose < nposes) {
        const float* gr = gt_rot  + (size_t)pose * (NJ * 6);
        const float* pp = pred_pos + (size_t)pose * (20 * 3);
        switch (wid) {
            case 0: sum = walk<0>(gr, pp, offsets); break;
            case 1: sum = walk<1>(gr, pp, offsets); break;
            case 2: sum = walk<2>(gr, pp, offsets); break;
            case 3: sum = walk<3>(gr, pp, offsets); break;
            case 4: sum = walk<4>(gr, pp, offsets); break;
        }
    }

    // wave (64-lane) reduction
#pragma unroll
    for (int o = 32; o > 0; o >>= 1) sum += __shfl_down(sum, o, 64);

    __shared__ float ws[5];
    if (lane == 0) ws[wid] = sum;
    __syncthreads();
    if (threadIdx.x == 0) {
        atomicAdd(out, (ws[0] + ws[1] + ws[2] + ws[3] + ws[4]) * scale);
    }
}

extern "C" void kernel_launch(void* const* d_in, const int* in_sizes, int n_in,
                              void* d_out, int out_size, void* d_ws, size_t ws_size,
                              hipStream_t stream) {
    const float* pred_pos = (const float*)d_in[0];
    const float* gt_rot   = (const float*)d_in[1];
    const float* offsets  = (const float*)d_in[2];
    float* out = (float*)d_out;

    int nposes = in_sizes[1] / (NJ * 6);   // B*S
    float scale = 1000.0f / ((float)nposes * 20.0f);

    hipMemsetAsync(out, 0, sizeof(float), stream);

    int block = 320;                        // 5 waves: one role each
    int grid = (nposes + 63) / 64;          // 64 poses per block
    mpjpe_fk_kernel<<<grid, block, 0, stream>>>(pred_pos, gt_rot, offsets, out, nposes, scale);
}

// Round 6
// 137.826 us; speedup vs baseline: 1.0521x; 1.0521x over previous
//
#include <hip/hip_runtime.h>

#define NJ 22

__device__ __forceinline__ void rot6d_to_mat(float a1x, float a1y, float a1z,
                                             float a2x, float a2y, float a2z,
                                             float* R) {
    float n1 = sqrtf(a1x * a1x + a1y * a1y + a1z * a1z);
    float inv1 = 1.0f / fmaxf(n1, 1e-12f);
    float b1x = a1x * inv1, b1y = a1y * inv1, b1z = a1z * inv1;
    float d = b1x * a2x + b1y * a2y + b1z * a2z;
    float b2x = a2x - b1x * d, b2y = a2y - b1y * d, b2z = a2z - b1z * d;
    float n2 = sqrtf(b2x * b2x + b2y * b2y + b2z * b2z);
    float inv2 = 1.0f / fmaxf(n2, 1e-12f);
    b2x *= inv2; b2y *= inv2; b2z *= inv2;
    float b3x = b1y * b2z - b1z * b2y;
    float b3y = b1z * b2x - b1x * b2z;
    float b3z = b1x * b2y - b1y * b2x;
    R[0] = b1x; R[1] = b2x; R[2] = b3x;
    R[3] = b1y; R[4] = b2y; R[5] = b3y;
    R[6] = b1z; R[7] = b2z; R[8] = b3z;
}

__device__ __forceinline__ void matmul3(const float* __restrict__ A,
                                        const float* __restrict__ B,
                                        float* __restrict__ C) {
#pragma unroll
    for (int r = 0; r < 3; ++r) {
#pragma unroll
        for (int c = 0; c < 3; ++c) {
            C[r * 3 + c] = A[r * 3 + 0] * B[0 * 3 + c]
                         + A[r * 3 + 1] * B[1 * 3 + c]
                         + A[r * 3 + 2] * B[2 * 3 + c];
        }
    }
}

// One thread per pose. All per-pose global data is fetched with 45 independent
// float4 loads (vs 120 narrow loads before): per-lane scattered access means
// every wave load instruction costs 64 L1 line-transactions, so transactions
// scale with instruction count — width is everything here.
__global__ __launch_bounds__(256) void mpjpe_fk_kernel(
    const float4* __restrict__ pred4,     // [NP*15]  (=[NP,20,3] floats, 240B/pose, 16B aligned)
    const float4* __restrict__ rot4,      // [NP*33]  (=[NP,22,6] floats, 528B/pose, 16B aligned)
    const float* __restrict__ offsets,    // [22,3]
    float* __restrict__ out,              // [1]
    int nposes, float scale)              // scale = 1000 / (NP*20)
{
    constexpr int PAR[NJ] = {-1, 0, 0, 0, 1, 2, 3, 4, 5, 6, 7, 8, 9, 9, 9, 12, 13, 14, 16, 17, 18, 19};

    int t = blockIdx.x * blockDim.x + threadIdx.x;
    float sum = 0.0f;

    if (t < nposes) {
        // ---- bulk preload: joints 2..21 of gt_rot (floats 12..131 of the pose
        // record -> float4s 3..32) and the whole pred record ----
        float rf[120];   // gt_rot floats, rf[6*j-12] is joint j's first float
        float pf[60];    // pred floats,  pf[3*(j-2)] is joint j's x
        const float4* gp = rot4 + (size_t)t * 33 + 3;
        const float4* pp = pred4 + (size_t)t * 15;
#pragma unroll
        for (int k = 0; k < 30; ++k) {
            float4 v = gp[k];
            rf[4*k+0] = v.x; rf[4*k+1] = v.y; rf[4*k+2] = v.z; rf[4*k+3] = v.w;
        }
#pragma unroll
        for (int k = 0; k < 15; ++k) {
            float4 v = pp[k];
            pf[4*k+0] = v.x; pf[4*k+1] = v.y; pf[4*k+2] = v.z; pf[4*k+3] = v.w;
        }

        float R[NJ][9];
        float P[NJ][3];

        R[0][0] = 1.f; R[0][1] = 0.f; R[0][2] = 0.f;
        R[0][3] = 0.f; R[0][4] = 1.f; R[0][5] = 0.f;
        R[0][6] = 0.f; R[0][7] = 0.f; R[0][8] = 1.f;
        P[0][0] = 0.f; P[0][1] = 0.f; P[0][2] = 0.f;

#pragma unroll
        for (int i = 1; i < NJ; ++i) {
            const int p = PAR[i];
            float ox = offsets[i * 3 + 0];
            float oy = offsets[i * 3 + 1];
            float oz = offsets[i * 3 + 2];
#pragma unroll
            for (int r = 0; r < 3; ++r) {
                P[i][r] = P[p][r] + R[p][r * 3 + 0] * ox
                                  + R[p][r * 3 + 1] * oy
                                  + R[p][r * 3 + 2] * oz;
            }
            if (i == 1) {
#pragma unroll
                for (int k = 0; k < 9; ++k) R[i][k] = R[p][k];
            } else {
                const int r0 = 6 * i - 12;   // compile-time after unroll
                float M[9];
                rot6d_to_mat(rf[r0+0], rf[r0+1], rf[r0+2],
                             rf[r0+3], rf[r0+4], rf[r0+5], M);
                matmul3(R[p], M, R[i]);
            }
            if (i >= 2) {
                const int q0 = 3 * i - 6;    // compile-time after unroll
                float dx = pf[q0+0] - P[i][0];
                float dy = pf[q0+1] - P[i][1];
                float dz = pf[q0+2] - P[i][2];
                sum += sqrtf(dx * dx + dy * dy + dz * dz);
            }
        }
    }

    // wave (64-lane) reduction
#pragma unroll
    for (int o = 32; o > 0; o >>= 1) sum += __shfl_down(sum, o, 64);

    __shared__ float ws[4];
    int lane = threadIdx.x & 63;
    int wid = threadIdx.x >> 6;
    if (lane == 0) ws[wid] = sum;
    __syncthreads();
    if (threadIdx.x == 0) {
        float s = ws[0] + ws[1] + ws[2] + ws[3];
        atomicAdd(out, s * scale);
    }
}

extern "C" void kernel_launch(void* const* d_in, const int* in_sizes, int n_in,
                              void* d_out, int out_size, void* d_ws, size_t ws_size,
                              hipStream_t stream) {
    const float4* pred4 = (const float4*)d_in[0];
    const float4* rot4  = (const float4*)d_in[1];
    const float* offsets = (const float*)d_in[2];
    float* out = (float*)d_out;

    int nposes = in_sizes[1] / (NJ * 6);   // B*S
    float scale = 1000.0f / ((float)nposes * 20.0f);

    hipMemsetAsync(out, 0, sizeof(float), stream);

    int block = 256;
    int grid = (nposes + block - 1) / block;
    mpjpe_fk_kernel<<<grid, block, 0, stream>>>(pred4, rot4, offsets, out, nposes, scale);
}

// Round 7
// 137.721 us; speedup vs baseline: 1.0529x; 1.0008x over previous
//
#include <hip/hip_runtime.h>

#define NJ 22

__device__ __forceinline__ void rot6d_to_mat(float a1x, float a1y, float a1z,
                                             float a2x, float a2y, float a2z,
                                             float* R) {
    float n1 = sqrtf(a1x * a1x + a1y * a1y + a1z * a1z);
    float inv1 = 1.0f / fmaxf(n1, 1e-12f);
    float b1x = a1x * inv1, b1y = a1y * inv1, b1z = a1z * inv1;
    float d = b1x * a2x + b1y * a2y + b1z * a2z;
    float b2x = a2x - b1x * d, b2y = a2y - b1y * d, b2z = a2z - b1z * d;
    float n2 = sqrtf(b2x * b2x + b2y * b2y + b2z * b2z);
    float inv2 = 1.0f / fmaxf(n2, 1e-12f);
    b2x *= inv2; b2y *= inv2; b2z *= inv2;
    float b3x = b1y * b2z - b1z * b2y;
    float b3y = b1z * b2x - b1x * b2z;
    float b3z = b1x * b2y - b1y * b2x;
    R[0] = b1x; R[1] = b2x; R[2] = b3x;
    R[3] = b1y; R[4] = b2y; R[5] = b3y;
    R[6] = b1z; R[7] = b2z; R[8] = b3z;
}

__device__ __forceinline__ void matmul3(const float* __restrict__ A,
                                        const float* __restrict__ B,
                                        float* __restrict__ C) {
#pragma unroll
    for (int r = 0; r < 3; ++r) {
#pragma unroll
        for (int c = 0; c < 3; ++c) {
            C[r * 3 + c] = A[r * 3 + 0] * B[0 * 3 + c]
                         + A[r * 3 + 1] * B[1 * 3 + c]
                         + A[r * 3 + 2] * B[2 * 3 + c];
        }
    }
}

// One thread per pose. __launch_bounds__(256,1) relaxes the VGPR budget so the
// compiler can keep the full 180-float preload LIVE in registers (~230 VGPR)
// and hoist all 45 dwordx4 loads to the top of the thread — one memory-latency
// wait per pose instead of ~20 serialized load->compute round-trips (the
// round-6 compile at 116 VGPR sank the loads back into the FK chain).
// 512 blocks = 2/CU; at <=256 VGPR -> 2 waves/SIMD -> whole grid co-resident.
__global__ __launch_bounds__(256, 1) void mpjpe_fk_kernel(
    const float4* __restrict__ pred4,     // [NP*15]  (=[NP,20,3] floats, 240B/pose)
    const float4* __restrict__ rot4,      // [NP*33]  (=[NP,22,6] floats, 528B/pose)
    const float* __restrict__ offsets,    // [22,3]
    float* __restrict__ out,              // [1]
    int nposes, float scale)              // scale = 1000 / (NP*20)
{
    constexpr int PAR[NJ] = {-1, 0, 0, 0, 1, 2, 3, 4, 5, 6, 7, 8, 9, 9, 9, 12, 13, 14, 16, 17, 18, 19};

    int t = blockIdx.x * blockDim.x + threadIdx.x;
    float sum = 0.0f;

    if (t < nposes) {
        // ---- bulk preload: joints 2..21 of gt_rot (float4s 3..32 of the 33-f4
        // pose record) and the whole pred record ----
        float rf[120];   // gt_rot floats, rf[6*j-12] is joint j's first float
        float pf[60];    // pred floats,  pf[3*(j-2)] is joint j's x
        const float4* gp = rot4 + (size_t)t * 33 + 3;
        const float4* pp = pred4 + (size_t)t * 15;
#pragma unroll
        for (int k = 0; k < 30; ++k) {
            float4 v = gp[k];
            rf[4*k+0] = v.x; rf[4*k+1] = v.y; rf[4*k+2] = v.z; rf[4*k+3] = v.w;
        }
#pragma unroll
        for (int k = 0; k < 15; ++k) {
            float4 v = pp[k];
            pf[4*k+0] = v.x; pf[4*k+1] = v.y; pf[4*k+2] = v.z; pf[4*k+3] = v.w;
        }

        float R[NJ][9];
        float P[NJ][3];

        R[0][0] = 1.f; R[0][1] = 0.f; R[0][2] = 0.f;
        R[0][3] = 0.f; R[0][4] = 1.f; R[0][5] = 0.f;
        R[0][6] = 0.f; R[0][7] = 0.f; R[0][8] = 1.f;
        P[0][0] = 0.f; P[0][1] = 0.f; P[0][2] = 0.f;

#pragma unroll
        for (int i = 1; i < NJ; ++i) {
            const int p = PAR[i];
            float ox = offsets[i * 3 + 0];
            float oy = offsets[i * 3 + 1];
            float oz = offsets[i * 3 + 2];
#pragma unroll
            for (int r = 0; r < 3; ++r) {
                P[i][r] = P[p][r] + R[p][r * 3 + 0] * ox
                                  + R[p][r * 3 + 1] * oy
                                  + R[p][r * 3 + 2] * oz;
            }
            if (i == 1) {
#pragma unroll
                for (int k = 0; k < 9; ++k) R[i][k] = R[p][k];
            } else {
                const int r0 = 6 * i - 12;   // compile-time after unroll
                float M[9];
                rot6d_to_mat(rf[r0+0], rf[r0+1], rf[r0+2],
                             rf[r0+3], rf[r0+4], rf[r0+5], M);
                matmul3(R[p], M, R[i]);
            }
            if (i >= 2) {
                const int q0 = 3 * i - 6;    // compile-time after unroll
                float dx = pf[q0+0] - P[i][0];
                float dy = pf[q0+1] - P[i][1];
                float dz = pf[q0+2] - P[i][2];
                sum += sqrtf(dx * dx + dy * dy + dz * dz);
            }
        }
    }

    // wave (64-lane) reduction
#pragma unroll
    for (int o = 32; o > 0; o >>= 1) sum += __shfl_down(sum, o, 64);

    __shared__ float ws[4];
    int lane = threadIdx.x & 63;
    int wid = threadIdx.x >> 6;
    if (lane == 0) ws[wid] = sum;
    __syncthreads();
    if (threadIdx.x == 0) {
        float s = ws[0] + ws[1] + ws[2] + ws[3];
        atomicAdd(out, s * scale);
    }
}

extern "C" void kernel_launch(void* const* d_in, const int* in_sizes, int n_in,
                              void* d_out, int out_size, void* d_ws, size_t ws_size,
                              hipStream_t stream) {
    const float4* pred4 = (const float4*)d_in[0];
    const float4* rot4  = (const float4*)d_in[1];
    const float* offsets = (const float*)d_in[2];
    float* out = (float*)d_out;

    int nposes = in_sizes[1] / (NJ * 6);   // B*S
    float scale = 1000.0f / ((float)nposes * 20.0f);

    hipMemsetAsync(out, 0, sizeof(float), stream);

    int block = 256;
    int grid = (nposes + block - 1) / block;
    mpjpe_fk_kernel<<<grid, block, 0, stream>>>(pred4, rot4, offsets, out, nposes, scale);
}

// Round 8
// 127.730 us; speedup vs baseline: 1.1353x; 1.0782x over previous
//
#include <hip/hip_runtime.h>

#define NJ 22

__device__ __forceinline__ void rot6d_to_mat(float a1x, float a1y, float a1z,
                                             float a2x, float a2y, float a2z,
                                             float* R) {
    float n1 = sqrtf(a1x * a1x + a1y * a1y + a1z * a1z);
    float inv1 = 1.0f / fmaxf(n1, 1e-12f);
    float b1x = a1x * inv1, b1y = a1y * inv1, b1z = a1z * inv1;
    float d = b1x * a2x + b1y * a2y + b1z * a2z;
    float b2x = a2x - b1x * d, b2y = a2y - b1y * d, b2z = a2z - b1z * d;
    float n2 = sqrtf(b2x * b2x + b2y * b2y + b2z * b2z);
    float inv2 = 1.0f / fmaxf(n2, 1e-12f);
    b2x *= inv2; b2y *= inv2; b2z *= inv2;
    float b3x = b1y * b2z - b1z * b2y;
    float b3y = b1z * b2x - b1x * b2z;
    float b3z = b1x * b2y - b1y * b2x;
    R[0] = b1x; R[1] = b2x; R[2] = b3x;
    R[3] = b1y; R[4] = b2y; R[5] = b3y;
    R[6] = b1z; R[7] = b2z; R[8] = b3z;
}

__device__ __forceinline__ void matmul3(const float* __restrict__ A,
                                        const float* __restrict__ B,
                                        float* __restrict__ C) {
#pragma unroll
    for (int r = 0; r < 3; ++r) {
#pragma unroll
        for (int c = 0; c < 3; ++c) {
            C[r * 3 + c] = A[r * 3 + 0] * B[0 * 3 + c]
                         + A[r * 3 + 1] * B[1 * 3 + c]
                         + A[r * 3 + 2] * B[2 * 3 + c];
        }
    }
}

// One thread per pose, 45 float4 preload, and — the actual experiment this
// time — a sched_barrier(0) fence between preload and FK compute. Rounds 6/7
// proved the compiler sinks the loads to their use sites (VGPR stayed 116),
// serializing ~20 memory latencies per pose. The fence forces all 45
// global_load_dwordx4 to issue before any FK math: one latency per pose,
// ~46KB in flight per wave.
__global__ __launch_bounds__(256, 1) void mpjpe_fk_kernel(
    const float4* __restrict__ pred4,     // [NP*15]  (=[NP,20,3] floats, 240B/pose)
    const float4* __restrict__ rot4,      // [NP*33]  (=[NP,22,6] floats, 528B/pose)
    const float* __restrict__ offsets,    // [22,3]
    float* __restrict__ out,              // [1]
    int nposes, float scale)              // scale = 1000 / (NP*20)
{
    constexpr int PAR[NJ] = {-1, 0, 0, 0, 1, 2, 3, 4, 5, 6, 7, 8, 9, 9, 9, 12, 13, 14, 16, 17, 18, 19};

    int t = blockIdx.x * blockDim.x + threadIdx.x;
    float sum = 0.0f;

    if (t < nposes) {
        // ---- bulk preload: joints 2..21 of gt_rot (float4s 3..32 of the 33-f4
        // pose record) and the whole pred record ----
        float rf[120];   // gt_rot floats, rf[6*j-12] is joint j's first float
        float pf[60];    // pred floats,  pf[3*(j-2)] is joint j's x
        const float4* gp = rot4 + (size_t)t * 33 + 3;
        const float4* pp = pred4 + (size_t)t * 15;
#pragma unroll
        for (int k = 0; k < 30; ++k) {
            float4 v = gp[k];
            rf[4*k+0] = v.x; rf[4*k+1] = v.y; rf[4*k+2] = v.z; rf[4*k+3] = v.w;
        }
#pragma unroll
        for (int k = 0; k < 15; ++k) {
            float4 v = pp[k];
            pf[4*k+0] = v.x; pf[4*k+1] = v.y; pf[4*k+2] = v.z; pf[4*k+3] = v.w;
        }

        // Scheduling fence: nothing (in particular no FK VALU op) may be
        // reordered before this point relative to the loads above — so all
        // 45 loads are in flight before the first dependent use.
        __builtin_amdgcn_sched_barrier(0);

        float R[NJ][9];
        float P[NJ][3];

        R[0][0] = 1.f; R[0][1] = 0.f; R[0][2] = 0.f;
        R[0][3] = 0.f; R[0][4] = 1.f; R[0][5] = 0.f;
        R[0][6] = 0.f; R[0][7] = 0.f; R[0][8] = 1.f;
        P[0][0] = 0.f; P[0][1] = 0.f; P[0][2] = 0.f;

#pragma unroll
        for (int i = 1; i < NJ; ++i) {
            const int p = PAR[i];
            float ox = offsets[i * 3 + 0];
            float oy = offsets[i * 3 + 1];
            float oz = offsets[i * 3 + 2];
#pragma unroll
            for (int r = 0; r < 3; ++r) {
                P[i][r] = P[p][r] + R[p][r * 3 + 0] * ox
                                  + R[p][r * 3 + 1] * oy
                                  + R[p][r * 3 + 2] * oz;
            }
            if (i == 1) {
#pragma unroll
                for (int k = 0; k < 9; ++k) R[i][k] = R[p][k];
            } else {
                const int r0 = 6 * i - 12;   // compile-time after unroll
                float M[9];
                rot6d_to_mat(rf[r0+0], rf[r0+1], rf[r0+2],
                             rf[r0+3], rf[r0+4], rf[r0+5], M);
                matmul3(R[p], M, R[i]);
            }
            if (i >= 2) {
                const int q0 = 3 * i - 6;    // compile-time after unroll
                float dx = pf[q0+0] - P[i][0];
                float dy = pf[q0+1] - P[i][1];
                float dz = pf[q0+2] - P[i][2];
                sum += sqrtf(dx * dx + dy * dy + dz * dz);
            }
        }
    }

    // wave (64-lane) reduction
#pragma unroll
    for (int o = 32; o > 0; o >>= 1) sum += __shfl_down(sum, o, 64);

    __shared__ float ws[4];
    int lane = threadIdx.x & 63;
    int wid = threadIdx.x >> 6;
    if (lane == 0) ws[wid] = sum;
    __syncthreads();
    if (threadIdx.x == 0) {
        float s = ws[0] + ws[1] + ws[2] + ws[3];
        atomicAdd(out, s * scale);
    }
}

extern "C" void kernel_launch(void* const* d_in, const int* in_sizes, int n_in,
                              void* d_out, int out_size, void* d_ws, size_t ws_size,
                              hipStream_t stream) {
    const float4* pred4 = (const float4*)d_in[0];
    const float4* rot4  = (const float4*)d_in[1];
    const float* offsets = (const float*)d_in[2];
    float* out = (float*)d_out;

    int nposes = in_sizes[1] / (NJ * 6);   // B*S
    float scale = 1000.0f / ((float)nposes * 20.0f);

    hipMemsetAsync(out, 0, sizeof(float), stream);

    int block = 256;
    int grid = (nposes + block - 1) / block;
    mpjpe_fk_kernel<<<grid, block, 0, stream>>>(pred4, rot4, offsets, out, nposes, scale);
}